// Round 6
// baseline (234.932 us; speedup 1.0000x reference)
//
#include <hip/hip_runtime.h>
#include <hip/hip_bf16.h>

#define BB 4
#define SS 2048
#define DM 1024
#define DN 64
#define WPB 8                 // waves per flash block
#define KPW (SS / WPB)        // 256 keys per wave

typedef short short8 __attribute__((ext_vector_type(8)));
typedef float f32x4 __attribute__((ext_vector_type(4)));
typedef unsigned short ushort;

__device__ __forceinline__ ushort f2bf(float f) {
    union { float f; unsigned u; } v; v.f = f;
    unsigned r = v.u + 0x7fffu + ((v.u >> 16) & 1u);
    return (ushort)(r >> 16);
}

// ---------------------------------------------------------------------------
// prep_w: convert w_q|w_k|w_v (each [64][1024] fp32) to bf16, same layout.
// ---------------------------------------------------------------------------
__global__ __launch_bounds__(256) void prep_w(
    const float* __restrict__ wq, const float* __restrict__ wk,
    const float* __restrict__ wv, ushort* __restrict__ w_bf)
{
    int i = blockIdx.x * 256 + threadIdx.x;          // 49152 threads, 4 floats each
    int p = i >> 14;                                  // 16384 float4 per proj
    int j = (i & 16383) * 4;
    const float* src = (p == 0) ? wq : (p == 1) ? wk : wv;
    float4 f = *(const float4*)(src + j);
    ushort o[4] = { f2bf(f.x), f2bf(f.y), f2bf(f.z), f2bf(f.w) };
    *(unsigned long long*)(w_bf + p * 65536 + j) = *(unsigned long long*)o;
}

// ---------------------------------------------------------------------------
// proj: out = x @ w^T + b. EXACT ROUND-0 STRUCTURE (best measured: 49.6us
// median). Falsified alternatives: occupancy x4 (R1), coalesced LDS staging
// (R2), async global_load_lds + counted vmcnt (R3), unroll 4 (R4). All
// neutral-to-worse -> fixed-latency regime; DO NOT TOUCH this kernel.
// Barrier-free: A-frags direct from global fp32, B-frags direct from bf16 w
// (L2-hot). One wave = 16 output rows, full K.
// qp/kp row-major bf16 [8192][64]; vp transposed [4][64][2048].
// ---------------------------------------------------------------------------
__global__ __launch_bounds__(128) void proj_kernel(
    const float* __restrict__ q, const float* __restrict__ k, const float* __restrict__ v,
    const ushort* __restrict__ w_bf,
    const float* __restrict__ bq, const float* __restrict__ bk, const float* __restrict__ bvp,
    ushort* __restrict__ qp, ushort* __restrict__ kp, ushort* __restrict__ vpT)
{
    const int tid  = threadIdx.x;
    const int proj = blockIdx.y;
    const int wv_id = tid >> 6;
    const int lane  = tid & 63;
    const int l16   = lane & 15;
    const int quad  = lane >> 4;
    const int g     = blockIdx.x * 2 + wv_id;   // 0..511 row-group
    const int m0    = g * 16;

    const float* x     = (proj == 0) ? q  : (proj == 1) ? k  : v;
    const ushort* wb   = w_bf + proj * 65536;
    const float* bias  = (proj == 0) ? bq : (proj == 1) ? bk : bvp;

    const float* arow = x + (size_t)(m0 + l16) * DM + quad * 8;

    f32x4 acc[4];
#pragma unroll
    for (int t = 0; t < 4; t++) acc[t] = (f32x4){0.f, 0.f, 0.f, 0.f};

#pragma unroll 2
    for (int kb = 0; kb < DM; kb += 32) {
        float4 f0 = *(const float4*)(arow + kb);
        float4 f1 = *(const float4*)(arow + kb + 4);
        ushort ta[8] = { f2bf(f0.x), f2bf(f0.y), f2bf(f0.z), f2bf(f0.w),
                         f2bf(f1.x), f2bf(f1.y), f2bf(f1.z), f2bf(f1.w) };
        short8 a = *(short8*)ta;
#pragma unroll
        for (int t = 0; t < 4; t++) {
            short8 b = *(const short8*)(wb + (size_t)(t * 16 + l16) * DM + kb + quad * 8);
            acc[t] = __builtin_amdgcn_mfma_f32_16x16x32_bf16(a, b, acc[t], 0, 0, 0);
        }
    }

    // C/D layout: n = t*16 + l16, row = quad*4 + r
#pragma unroll
    for (int t = 0; t < 4; t++) {
        int n = t * 16 + l16;
        float bb_ = bias[n];
#pragma unroll
        for (int r = 0; r < 4; r++) {
            int grow = m0 + quad * 4 + r;
            ushort h = f2bf(acc[t][r] + bb_);
            if (proj == 0)      qp[(size_t)grow * DN + n] = h;
            else if (proj == 1) kp[(size_t)grow * DN + n] = h;
            else {
                int bb = grow >> 11, s = grow & 2047;
                vpT[((size_t)bb * DN + n) * SS + s] = h;
            }
        }
    }
}

// ---------------------------------------------------------------------------
// flash: one block = one q-group (16 rows); 8 waves each own a 256-key
// slice (barrier-free main loop). vs R5 (50.3us, occ 20%, VALU 14.6%):
// (1) 8 waves/block -> 4096 waves, 50% occ ceiling (TLP for the serial
//     mask->QK->softmax->PV chain; flash never had the occupancy probe);
// (2) T14 mask prefetch: next iter's 16 mask f32 loaded after this iter's
//     V-frags (issue order K,V,mask_next -> K/V vmcnt waits don't drain
//     the prefetch); mask HBM latency hides under softmax+PV;
// (3) p_lds row stride 80->72 ushorts (odd x16B): P-read 4-way -> 2-way.
// In-block merge of 8 (O,m,l) partials after one __syncthreads.
// ---------------------------------------------------------------------------
__global__ __launch_bounds__(512, 4) void flash_kernel(
    const float* __restrict__ mask,
    const ushort* __restrict__ qp,
    const ushort* __restrict__ kp,
    const ushort* __restrict__ vpT,
    float* __restrict__ out)        // [8192][64] fp32, final
{
    __shared__ __align__(16) ushort p_lds[WPB][16][72]; // 144B stride: 2-way on b128
    __shared__ __align__(16) float sO[WPB][16][68];     // +4 pad
    __shared__ float sm[WPB][16];
    __shared__ float sl[WPB][16];

    const int tid  = threadIdx.x;
    const int wv   = tid >> 6;                    // 0..7 = key-slice
    const int lane = tid & 63;
    const int l16  = lane & 15;
    const int quad = lane >> 4;

    const int qg = blockIdx.x & 127;              // q-group within batch (128/batch)
    const int b  = blockIdx.x >> 7;

    // Q fragments (A-layout), direct from global
    const ushort* qbase = qp + ((size_t)b * SS + qg * 16 + l16) * DN + quad * 8;
    short8 aq0 = *(const short8*)(qbase);
    short8 aq1 = *(const short8*)(qbase + 32);

    float m_r[4] = { -__builtin_inff(), -__builtin_inff(),
                     -__builtin_inff(), -__builtin_inff() };
    float l_r[4] = { 0.f, 0.f, 0.f, 0.f };
    f32x4 Oacc[4];
#pragma unroll
    for (int t = 0; t < 4; t++) Oacc[t] = (f32x4){0.f, 0.f, 0.f, 0.f};

    const size_t mrow0 = ((size_t)b * SS + qg * 16 + quad * 4) * SS;
    const int k_begin = wv * KPW;

    // preload first iteration's mask (fp32: argmax decided by ~1e2 gaps)
    float mk[4][4];
#pragma unroll
    for (int t = 0; t < 4; t++)
#pragma unroll
        for (int r = 0; r < 4; r++)
            mk[t][r] = mask[mrow0 + (size_t)r * SS + k_begin + t * 16 + l16];

    for (int it = 0; it < KPW / 64; it++) {
        const int k0 = k_begin + it * 64;

        // S = qp . kp^T ; B-frags direct from global kp (row-major, L2-hot)
        f32x4 sc[4];
#pragma unroll
        for (int t = 0; t < 4; t++) {
            const ushort* kb_ = kp + ((size_t)b * SS + k0 + t * 16 + l16) * DN + quad * 8;
            short8 bk0 = *(const short8*)(kb_);
            short8 bk1 = *(const short8*)(kb_ + 32);
            f32x4 z = (f32x4){0.f, 0.f, 0.f, 0.f};
            z = __builtin_amdgcn_mfma_f32_16x16x32_bf16(aq0, bk0, z, 0, 0, 0);
            z = __builtin_amdgcn_mfma_f32_16x16x32_bf16(aq1, bk1, z, 0, 0, 0);
            sc[t] = z;
        }

        // hoist V-frags into regs (issued before the mask prefetch so the
        // PV vmcnt wait does not drain the prefetch)
        short8 bv0[4], bv1[4];
#pragma unroll
        for (int tf = 0; tf < 4; tf++) {
            const ushort* vb_ = vpT + ((size_t)b * DN + tf * 16 + l16) * SS + k0 + quad * 8;
            bv0[tf] = *(const short8*)(vb_);
            bv1[tf] = *(const short8*)(vb_ + 32);
        }

        // T14: prefetch next iteration's mask; consumed next iter after QK
        float mkn[4][4];
        if (it < KPW / 64 - 1) {
#pragma unroll
            for (int t = 0; t < 4; t++)
#pragma unroll
                for (int r = 0; r < 4; r++)
                    mkn[t][r] = mask[mrow0 + (size_t)r * SS + (k0 + 64) + t * 16 + l16];
        }

        // online softmax per accumulator reg (one q row per reg), mask in regs
#pragma unroll
        for (int r = 0; r < 4; r++) {
            float s[4];
            float tmax = -__builtin_inff();
#pragma unroll
            for (int t = 0; t < 4; t++) {
                s[t] = sc[t][r] * 0.125f - 1e9f * mk[t][r];
                tmax = fmaxf(tmax, s[t]);
            }
#pragma unroll
            for (int off = 8; off >= 1; off >>= 1)
                tmax = fmaxf(tmax, __shfl_xor(tmax, off, 16));
            float mnew  = fmaxf(m_r[r], tmax);
            float alpha = __expf(m_r[r] - mnew);
            m_r[r] = mnew;
            float rs = 0.f;
#pragma unroll
            for (int t = 0; t < 4; t++) {
                float pv = __expf(s[t] - mnew);
                rs += pv;
                p_lds[wv][quad * 4 + r][t * 16 + l16] = f2bf(pv);
            }
#pragma unroll
            for (int off = 8; off >= 1; off >>= 1)
                rs += __shfl_xor(rs, off, 16);
            l_r[r] = l_r[r] * alpha + rs;
#pragma unroll
            for (int tf = 0; tf < 4; tf++)
                Oacc[tf][r] *= alpha;
        }
        // wave-private LDS roundtrip: in-order DS pipe, no barrier needed

        short8 ap0 = *(const short8*)&p_lds[wv][l16][quad * 8];
        short8 ap1 = *(const short8*)&p_lds[wv][l16][32 + quad * 8];
#pragma unroll
        for (int tf = 0; tf < 4; tf++) {
            Oacc[tf] = __builtin_amdgcn_mfma_f32_16x16x32_bf16(ap0, bv0[tf], Oacc[tf], 0, 0, 0);
            Oacc[tf] = __builtin_amdgcn_mfma_f32_16x16x32_bf16(ap1, bv1[tf], Oacc[tf], 0, 0, 0);
        }

        if (it < KPW / 64 - 1) {
#pragma unroll
            for (int t = 0; t < 4; t++)
#pragma unroll
                for (int r = 0; r < 4; r++)
                    mk[t][r] = mkn[t][r];
        }
    }

    // park partials in LDS: row = quad*4+r, col = tf*16+l16 (C/D layout)
#pragma unroll
    for (int r = 0; r < 4; r++) {
        if (l16 == 0) {
            sm[wv][quad * 4 + r] = m_r[r];
            sl[wv][quad * 4 + r] = l_r[r];
        }
#pragma unroll
        for (int tf = 0; tf < 4; tf++)
            sO[wv][quad * 4 + r][tf * 16 + l16] = Oacc[tf][r];
    }
    __syncthreads();

    // in-block combine: 512 threads; group (tid>>6) handles 2 rows, col = tid&63
    const int col = tid & 63;
    const int grp = tid >> 6;
#pragma unroll
    for (int rr = 0; rr < 2; rr++) {
        const int row = grp * 2 + rr;
        float M = -__builtin_inff();
#pragma unroll
        for (int i = 0; i < WPB; i++) M = fmaxf(M, sm[i][row]);
        float L = 0.f, acc = 0.f;
#pragma unroll
        for (int i = 0; i < WPB; i++) {
            float e = __expf(sm[i][row] - M);
            L   += e * sl[i][row];
            acc += e * sO[i][row][col];
        }
        out[((size_t)b * SS + qg * 16 + row) * DN + col] = acc / L;
    }
}

extern "C" void kernel_launch(void* const* d_in, const int* in_sizes, int n_in,
                              void* d_out, int out_size, void* d_ws, size_t ws_size,
                              hipStream_t stream) {
    const float* q    = (const float*)d_in[0];
    const float* k    = (const float*)d_in[1];
    const float* v    = (const float*)d_in[2];
    const float* mask = (const float*)d_in[3];
    const float* wq   = (const float*)d_in[4];
    const float* bq   = (const float*)d_in[5];
    const float* wk   = (const float*)d_in[6];
    const float* bk   = (const float*)d_in[7];
    const float* wv   = (const float*)d_in[8];
    const float* bv   = (const float*)d_in[9];
    float* out = (float*)d_out;

    // workspace layout (no partials needed: k-split merged in-block)
    char* p = (char*)d_ws;
    ushort* w_bf = (ushort*)p;                 p += 3 * 65536 * sizeof(ushort);   // 384 KB
    ushort* qp   = (ushort*)p;                 p += (size_t)BB * SS * DN * 2;     // 1 MB
    ushort* kp   = (ushort*)p;                 p += (size_t)BB * SS * DN * 2;     // 1 MB
    ushort* vpT  = (ushort*)p;                 p += (size_t)BB * SS * DN * 2;     // 1 MB

    prep_w<<<192, 256, 0, stream>>>(wq, wk, wv, w_bf);
    proj_kernel<<<dim3(256, 3), 128, 0, stream>>>(q, k, v, w_bf, bq, bk, bv, qp, kp, vpT);
    flash_kernel<<<BB * 128, 512, 0, stream>>>(mask, qp, kp, vpT, out);
}

// Round 7
// 222.853 us; speedup vs baseline: 1.0542x; 1.0542x over previous
//
#include <hip/hip_runtime.h>
#include <hip/hip_bf16.h>

#define BB 4
#define SS 2048
#define DM 1024
#define DN 64
#define WPB 8                 // waves per flash block
#define KPW (SS / WPB)        // 256 keys per wave

typedef short short8 __attribute__((ext_vector_type(8)));
typedef float f32x4 __attribute__((ext_vector_type(4)));
typedef unsigned short ushort;

__device__ __forceinline__ ushort f2bf(float f) {
    union { float f; unsigned u; } v; v.f = f;
    unsigned r = v.u + 0x7fffu + ((v.u >> 16) & 1u);
    return (ushort)(r >> 16);
}

// ---------------------------------------------------------------------------
// prep_w: convert w_q|w_k|w_v (each [64][1024] fp32) to bf16, same layout.
// ---------------------------------------------------------------------------
__global__ __launch_bounds__(256) void prep_w(
    const float* __restrict__ wq, const float* __restrict__ wk,
    const float* __restrict__ wv, ushort* __restrict__ w_bf)
{
    int i = blockIdx.x * 256 + threadIdx.x;          // 49152 threads, 4 floats each
    int p = i >> 14;                                  // 16384 float4 per proj
    int j = (i & 16383) * 4;
    const float* src = (p == 0) ? wq : (p == 1) ? wk : wv;
    float4 f = *(const float4*)(src + j);
    ushort o[4] = { f2bf(f.x), f2bf(f.y), f2bf(f.z), f2bf(f.w) };
    *(unsigned long long*)(w_bf + p * 65536 + j) = *(unsigned long long*)o;
}

// ---------------------------------------------------------------------------
// proj: out = x @ w^T + b. EXACT ROUND-0 STRUCTURE (best measured: 49.6us
// median). Falsified alternatives: occupancy x4 (R1), coalesced LDS staging
// (R2), async global_load_lds + counted vmcnt (R3), unroll 4 (R4). All
// neutral-to-worse -> fixed-latency regime; DO NOT TOUCH this kernel.
// Barrier-free: A-frags direct from global fp32, B-frags direct from bf16 w
// (L2-hot). One wave = 16 output rows, full K.
// qp/kp row-major bf16 [8192][64]; vp transposed [4][64][2048].
// ---------------------------------------------------------------------------
__global__ __launch_bounds__(128) void proj_kernel(
    const float* __restrict__ q, const float* __restrict__ k, const float* __restrict__ v,
    const ushort* __restrict__ w_bf,
    const float* __restrict__ bq, const float* __restrict__ bk, const float* __restrict__ bvp,
    ushort* __restrict__ qp, ushort* __restrict__ kp, ushort* __restrict__ vpT)
{
    const int tid  = threadIdx.x;
    const int proj = blockIdx.y;
    const int wv_id = tid >> 6;
    const int lane  = tid & 63;
    const int l16   = lane & 15;
    const int quad  = lane >> 4;
    const int g     = blockIdx.x * 2 + wv_id;   // 0..511 row-group
    const int m0    = g * 16;

    const float* x     = (proj == 0) ? q  : (proj == 1) ? k  : v;
    const ushort* wb   = w_bf + proj * 65536;
    const float* bias  = (proj == 0) ? bq : (proj == 1) ? bk : bvp;

    const float* arow = x + (size_t)(m0 + l16) * DM + quad * 8;

    f32x4 acc[4];
#pragma unroll
    for (int t = 0; t < 4; t++) acc[t] = (f32x4){0.f, 0.f, 0.f, 0.f};

#pragma unroll 2
    for (int kb = 0; kb < DM; kb += 32) {
        float4 f0 = *(const float4*)(arow + kb);
        float4 f1 = *(const float4*)(arow + kb + 4);
        ushort ta[8] = { f2bf(f0.x), f2bf(f0.y), f2bf(f0.z), f2bf(f0.w),
                         f2bf(f1.x), f2bf(f1.y), f2bf(f1.z), f2bf(f1.w) };
        short8 a = *(short8*)ta;
#pragma unroll
        for (int t = 0; t < 4; t++) {
            short8 b = *(const short8*)(wb + (size_t)(t * 16 + l16) * DM + kb + quad * 8);
            acc[t] = __builtin_amdgcn_mfma_f32_16x16x32_bf16(a, b, acc[t], 0, 0, 0);
        }
    }

    // C/D layout: n = t*16 + l16, row = quad*4 + r
#pragma unroll
    for (int t = 0; t < 4; t++) {
        int n = t * 16 + l16;
        float bb_ = bias[n];
#pragma unroll
        for (int r = 0; r < 4; r++) {
            int grow = m0 + quad * 4 + r;
            ushort h = f2bf(acc[t][r] + bb_);
            if (proj == 0)      qp[(size_t)grow * DN + n] = h;
            else if (proj == 1) kp[(size_t)grow * DN + n] = h;
            else {
                int bb = grow >> 11, s = grow & 2047;
                vpT[((size_t)bb * DN + n) * SS + s] = h;
            }
        }
    }
}

// ---------------------------------------------------------------------------
// flash: one block = one q-group (16 rows); 8 waves each own a 256-key
// slice (barrier-free main loop, wave-private LDS P roundtrip).
// R6 post-mortem: 8-wave variant spilled (VGPR forced to 64 by
// launch_bounds(512,4) + mask-prefetch + V-hoisting -> WRITE_SIZE 23MB of
// scratch, dur 60.8us). R7 = same 8-wave structure, spill removed:
//   - no mask prefetch, V-frags loaded inline at PV (R5's 52-VGPR pattern)
//   - launch_bounds(512,2): cap 256 VGPR; natural usage ~<=128 -> 2 blk/CU
//   - keep p_lds stride 72 (bank conflicts 524K -> 131K, verified R6)
// This is the clean 8-wave-vs-4-wave TLP test that R6 failed to run.
// In-block merge of 8 (O,m,l) partials after one __syncthreads.
// ---------------------------------------------------------------------------
__global__ __launch_bounds__(512, 2) void flash_kernel(
    const float* __restrict__ mask,
    const ushort* __restrict__ qp,
    const ushort* __restrict__ kp,
    const ushort* __restrict__ vpT,
    float* __restrict__ out)        // [8192][64] fp32, final
{
    __shared__ __align__(16) ushort p_lds[WPB][16][72]; // 144B stride: 2-way on b128
    __shared__ __align__(16) float sO[WPB][16][68];     // +4 pad
    __shared__ float sm[WPB][16];
    __shared__ float sl[WPB][16];

    const int tid  = threadIdx.x;
    const int wv   = tid >> 6;                    // 0..7 = key-slice
    const int lane = tid & 63;
    const int l16  = lane & 15;
    const int quad = lane >> 4;

    const int qg = blockIdx.x & 127;              // q-group within batch (128/batch)
    const int b  = blockIdx.x >> 7;

    // Q fragments (A-layout), direct from global
    const ushort* qbase = qp + ((size_t)b * SS + qg * 16 + l16) * DN + quad * 8;
    short8 aq0 = *(const short8*)(qbase);
    short8 aq1 = *(const short8*)(qbase + 32);

    float m_r[4] = { -__builtin_inff(), -__builtin_inff(),
                     -__builtin_inff(), -__builtin_inff() };
    float l_r[4] = { 0.f, 0.f, 0.f, 0.f };
    f32x4 Oacc[4];
#pragma unroll
    for (int t = 0; t < 4; t++) Oacc[t] = (f32x4){0.f, 0.f, 0.f, 0.f};

    const size_t mrow0 = ((size_t)b * SS + qg * 16 + quad * 4) * SS;
    const int k_begin = wv * KPW;
    const int k_end   = k_begin + KPW;

    for (int k0 = k_begin; k0 < k_end; k0 += 64) {
        // fp32 mask loads (argmax decided by ~1e2 score gaps -> must stay fp32)
        float mk[4][4];
#pragma unroll
        for (int t = 0; t < 4; t++)
#pragma unroll
            for (int r = 0; r < 4; r++)
                mk[t][r] = mask[mrow0 + (size_t)r * SS + k0 + t * 16 + l16];

        // S = qp . kp^T ; B-frags direct from global kp (row-major, L2-hot)
        f32x4 sc[4];
#pragma unroll
        for (int t = 0; t < 4; t++) {
            const ushort* kb_ = kp + ((size_t)b * SS + k0 + t * 16 + l16) * DN + quad * 8;
            short8 bk0 = *(const short8*)(kb_);
            short8 bk1 = *(const short8*)(kb_ + 32);
            f32x4 z = (f32x4){0.f, 0.f, 0.f, 0.f};
            z = __builtin_amdgcn_mfma_f32_16x16x32_bf16(aq0, bk0, z, 0, 0, 0);
            z = __builtin_amdgcn_mfma_f32_16x16x32_bf16(aq1, bk1, z, 0, 0, 0);
            sc[t] = z;
        }

        // online softmax per accumulator reg (one q row per reg)
#pragma unroll
        for (int r = 0; r < 4; r++) {
            float s[4];
            float tmax = -__builtin_inff();
#pragma unroll
            for (int t = 0; t < 4; t++) {
                s[t] = sc[t][r] * 0.125f - 1e9f * mk[t][r];
                tmax = fmaxf(tmax, s[t]);
            }
#pragma unroll
            for (int off = 8; off >= 1; off >>= 1)
                tmax = fmaxf(tmax, __shfl_xor(tmax, off, 16));
            float mnew  = fmaxf(m_r[r], tmax);
            float alpha = __expf(m_r[r] - mnew);
            m_r[r] = mnew;
            float rs = 0.f;
#pragma unroll
            for (int t = 0; t < 4; t++) {
                float pv = __expf(s[t] - mnew);
                rs += pv;
                p_lds[wv][quad * 4 + r][t * 16 + l16] = f2bf(pv);
            }
#pragma unroll
            for (int off = 8; off >= 1; off >>= 1)
                rs += __shfl_xor(rs, off, 16);
            l_r[r] = l_r[r] * alpha + rs;
#pragma unroll
            for (int tf = 0; tf < 4; tf++)
                Oacc[tf][r] *= alpha;
        }
        // wave-private LDS roundtrip: in-order DS pipe, no barrier needed

        short8 ap0 = *(const short8*)&p_lds[wv][l16][quad * 8];
        short8 ap1 = *(const short8*)&p_lds[wv][l16][32 + quad * 8];
#pragma unroll
        for (int tf = 0; tf < 4; tf++) {
            const ushort* vb_ = vpT + ((size_t)b * DN + tf * 16 + l16) * SS + k0 + quad * 8;
            short8 bv0 = *(const short8*)(vb_);
            short8 bv1 = *(const short8*)(vb_ + 32);
            Oacc[tf] = __builtin_amdgcn_mfma_f32_16x16x32_bf16(ap0, bv0, Oacc[tf], 0, 0, 0);
            Oacc[tf] = __builtin_amdgcn_mfma_f32_16x16x32_bf16(ap1, bv1, Oacc[tf], 0, 0, 0);
        }
    }

    // park partials in LDS: row = quad*4+r, col = tf*16+l16 (C/D layout)
#pragma unroll
    for (int r = 0; r < 4; r++) {
        if (l16 == 0) {
            sm[wv][quad * 4 + r] = m_r[r];
            sl[wv][quad * 4 + r] = l_r[r];
        }
#pragma unroll
        for (int tf = 0; tf < 4; tf++)
            sO[wv][quad * 4 + r][tf * 16 + l16] = Oacc[tf][r];
    }
    __syncthreads();

    // in-block combine: 512 threads; group (tid>>6) handles 2 rows, col = tid&63
    const int col = tid & 63;
    const int grp = tid >> 6;
#pragma unroll
    for (int rr = 0; rr < 2; rr++) {
        const int row = grp * 2 + rr;
        float M = -__builtin_inff();
#pragma unroll
        for (int i = 0; i < WPB; i++) M = fmaxf(M, sm[i][row]);
        float L = 0.f, acc = 0.f;
#pragma unroll
        for (int i = 0; i < WPB; i++) {
            float e = __expf(sm[i][row] - M);
            L   += e * sl[i][row];
            acc += e * sO[i][row][col];
        }
        out[((size_t)b * SS + qg * 16 + row) * DN + col] = acc / L;
    }
}

extern "C" void kernel_launch(void* const* d_in, const int* in_sizes, int n_in,
                              void* d_out, int out_size, void* d_ws, size_t ws_size,
                              hipStream_t stream) {
    const float* q    = (const float*)d_in[0];
    const float* k    = (const float*)d_in[1];
    const float* v    = (const float*)d_in[2];
    const float* mask = (const float*)d_in[3];
    const float* wq   = (const float*)d_in[4];
    const float* bq   = (const float*)d_in[5];
    const float* wk   = (const float*)d_in[6];
    const float* bk   = (const float*)d_in[7];
    const float* wv   = (const float*)d_in[8];
    const float* bv   = (const float*)d_in[9];
    float* out = (float*)d_out;

    // workspace layout (no partials needed: k-split merged in-block)
    char* p = (char*)d_ws;
    ushort* w_bf = (ushort*)p;                 p += 3 * 65536 * sizeof(ushort);   // 384 KB
    ushort* qp   = (ushort*)p;                 p += (size_t)BB * SS * DN * 2;     // 1 MB
    ushort* kp   = (ushort*)p;                 p += (size_t)BB * SS * DN * 2;     // 1 MB
    ushort* vpT  = (ushort*)p;                 p += (size_t)BB * SS * DN * 2;     // 1 MB

    prep_w<<<192, 256, 0, stream>>>(wq, wk, wv, w_bf);
    proj_kernel<<<dim3(256, 3), 128, 0, stream>>>(q, k, v, w_bf, bq, bk, bv, qp, kp, vpT);
    flash_kernel<<<BB * 128, 512, 0, stream>>>(mask, qp, kp, vpT, out);
}